// Round 8
// baseline (330.886 us; speedup 1.0000x reference)
//
#include <hip/hip_runtime.h>

// EdgeGate: out[e] = silu(f(e) @ W1 + b1) @ W2 + b2,
//   f(e) = [|H_u - H_v| (128), H_u*H_v (128), S_e, F_e]   (258)
//
// R20 (from R19: main 130us, total 291us, MfmaUtil 14.2, VALU 35.7,
// Occupancy 41.7 -- latency-bound, no pipe half-busy).
//  (1) OCCUPANCY DOUBLING: LDS (74KB) caps residency at 2 blocks/CU; with
//      512-thread blocks that's 16 waves/CU = 4/SIMD. Switch to 1024-thread
//      blocks, SAME single w1t: 2 blocks/CU still fit LDS (148<=160KB) but
//      now 32 waves/CU = 8/SIMD -- 2x latency hiding for the per-tile
//      serial chain (recs gather -> H gathers -> LDS-fed MFMA -> trans
//      epilogue). VGPR 60 <= 64 cap of __launch_bounds__(1024,8): no spill
//      expected (R17's spill needed ~130 regs; watched via WRITE_SIZE).
//      Tickets 256 edges (16 waves x 16), grid 256 (~32 blocks/XCD).
//  (2) pre-pass reverted to R16's proven-faster shape (R18's shuffle cost
//      +11us): memset + cvt_hist (cvt overlapped early) + R18's validated
//      fused scan + plain scatter. 5 ops.
// Kept: R19 operand swap (epilogue = 32 silu-fma + 2 shfl_xor, lane owns
// its edge), ordered ticket queue + prefetch (PACING; R14/R15 proved
// static partitions thrash L2), S/F/b1 in MFMA K-chunk 8.

typedef _Float16       half8   __attribute__((ext_vector_type(8)));
typedef _Float16       half4v  __attribute__((ext_vector_type(4)));
typedef unsigned short ushort8 __attribute__((ext_vector_type(8)));
typedef float          f32x4   __attribute__((ext_vector_type(4)));

#define NSEG       8
#define W1T_STRIDE 288   // halves per n-row: 9 K-chunks x 32

__device__ __forceinline__ float silu_f(float x) {
    return x / (1.0f + __expf(-x));
}

__device__ __forceinline__ void canon(int u, int v, int& a, int& b) {
    const int sw = (u ^ v) & 1;       // balanced, symmetric in (u,v)
    a = sw ? v : u;
    b = sw ? u : v;
}

// ---------------- pre-passes ----------------
// hist[0..NB) + ctr(8) + flag(1) zeroed by one hipMemsetAsync.

// cvt fused with hist (R16 form: cvt overlaps the sort pipeline's front)
__global__ __launch_bounds__(256)
void cvt_hist_kernel(const float* __restrict__ H, _Float16* __restrict__ Hh,
                     int n4, const int* __restrict__ eidx,
                     int* __restrict__ hist, int E, int ASZ, int BBINS) {
    int i = blockIdx.x * blockDim.x + threadIdx.x;
    if (i < n4) {
        const float4 f = ((const float4*)H)[i];
        half4v h;
        h[0] = (_Float16)f.x; h[1] = (_Float16)f.y;
        h[2] = (_Float16)f.z; h[3] = (_Float16)f.w;
        ((half4v*)Hh)[i] = h;
    }
    if (i < E) {
        int a, b;
        canon(eidx[i], eidx[E + i], a, b);
        atomicAdd(&hist[(a / ASZ) * BBINS + (b >> 3)], 1);
    }
}

// fused scan1+scan2 (R18, validated): per-block exclusive scan, last block
// scans bsum and emits vbs. Cross-block reads via atomic RMW after
// threadfence/flag handshake.
__global__ __launch_bounds__(256)
void scan_kernel(int* __restrict__ hist, int* __restrict__ bsum,
                 int NB, int nb1, int* __restrict__ flag,
                 int* __restrict__ vbs, int BBINS, int E) {
    __shared__ int s[256];
    __shared__ int lastBlk;
    const int t = threadIdx.x;
    const int i = blockIdx.x * 256 + t;
    const int v = (i < NB) ? hist[i] : 0;
    s[t] = v;
    __syncthreads();
    for (int off = 1; off < 256; off <<= 1) {
        const int x = (t >= off) ? s[t - off] : 0;
        __syncthreads();
        s[t] += x;
        __syncthreads();
    }
    if (i < NB) hist[i] = s[t] - v;       // intra-block exclusive
    if (t == 255) bsum[blockIdx.x] = s[255];
    __threadfence();                       // publish before flag
    if (t == 0) lastBlk = (atomicAdd(flag, 1) == (int)gridDim.x - 1);
    __syncthreads();
    if (!lastBlk) return;
    const int bv = (t < nb1) ? atomicAdd(&bsum[t], 0) : 0;   // coherent read
    s[t] = bv;
    __syncthreads();
    for (int off = 1; off < 256; off <<= 1) {
        const int x = (t >= off) ? s[t - off] : 0;
        __syncthreads();
        s[t] += x;
        __syncthreads();
    }
    if (t < nb1) bsum[t] = s[t] - bv;     // exclusive
    __syncthreads();
    if (t < NSEG) {
        const int idx = t * BBINS;
        vbs[t] = atomicAdd(&hist[idx], 0) + bsum[idx >> 8];
    } else if (t == NSEG) {
        vbs[NSEG] = E;
    }
}

__global__ __launch_bounds__(256)
void scatter_kernel(const int* __restrict__ eidx, const float* __restrict__ Se,
                    const float* __restrict__ Fe, int* __restrict__ ofs,
                    const int* __restrict__ bsum,
                    int4* __restrict__ recs, int E, int ASZ, int BBINS) {
    int e = blockIdx.x * blockDim.x + threadIdx.x;
    if (e < E) {
        int a, b;
        canon(eidx[e], eidx[E + e], a, b);
        const int key = (a / ASZ) * BBINS + (b >> 3);
        const int pos = atomicAdd(&ofs[key], 1) + bsum[key >> 8];
        _Float16 sh = (_Float16)Se[e];
        _Float16 fh = (_Float16)Fe[e];
        unsigned pk = (unsigned)*(unsigned short*)&sh
                    | ((unsigned)*(unsigned short*)&fh << 16);
        recs[pos] = make_int4(a, b, e, (int)pk);
    }
}

// ---------------- W1 LDS staging (1024-thread version) ----------------
// w1t[n][kp] f16, kp = c*32 + k32, c = 0..8.
// c<8: src row = (c&1)*128 + (c>>1)*32 + k32. 16B blocks kb at kb^(n&7).
// c==8 (kb 32..35, UNswizzled): k32==0 -> W1 row 256, k32==1 -> row 257,
//      k32==2 -> b1, else 0.

__device__ __forceinline__ void stage_w1(const float* __restrict__ W1,
                                         const float* __restrict__ b1,
                                         _Float16* __restrict__ w1t, int tid) {
    const int n = tid & 127;
    const int g = tid >> 7;                // 0..7 (1024 threads)
    #pragma unroll
    for (int i = 0; i < 5; ++i) {
        const int kb = g + (i << 3);       // 0..39
        if (kb < 32) {
            half8 tmp;
            #pragma unroll
            for (int j = 0; j < 8; ++j) {
                const int kp  = (kb << 3) + j;
                const int c   = kp >> 5;
                const int k32 = kp & 31;
                const int src = ((c & 1) << 7) + ((c >> 1) << 5) + k32;
                tmp[j] = (_Float16)W1[src * 128 + n];
            }
            *(half8*)&w1t[n * W1T_STRIDE + ((kb ^ (n & 7)) << 3)] = tmp;
        } else if (kb < 36) {
            const int k32b = (kb - 32) << 3;   // 0,8,16,24
            half8 tmp;
            #pragma unroll
            for (int j = 0; j < 8; ++j) {
                const int k32 = k32b + j;
                float v = 0.f;
                if (k32 == 0)      v = W1[32768 + n];   // row 256
                else if (k32 == 1) v = W1[32896 + n];   // row 257
                else if (k32 == 2) v = b1[n];
                tmp[j] = (_Float16)v;
            }
            *(half8*)&w1t[n * W1T_STRIDE + (kb << 3)] = tmp;
        }
    }
}

// ---------------- main tile compute (one 16-edge group per wave) ----------------
// SWAPPED operands (R19): mfma(w_frag, edge_frag, acc) -> C[hidden][edge].
// Lane (q,cb): acc[t][rr] = h[hidden = t*16 + q*4 + rr][edge = cb].

__device__ __forceinline__ void edge_tile16(
    const _Float16* __restrict__ Hh, const int4* __restrict__ recs,
    const _Float16* __restrict__ w1t,
    const f32x4* __restrict__ w2r, float b2v, float* __restrict__ out,
    int ebase, int elim, int q, int cb, int swz)
{
    const int e = min(ebase + cb, elim - 1);     // clamp; store guarded
    const int4 r = recs[e];
    const int a = r.x, b = r.y;
    const unsigned pk = (unsigned)r.w;
    const unsigned short sl = (unsigned short)(pk & 0xFFFF);
    const unsigned short fl = (unsigned short)(pk >> 16);

    const _Float16* up = Hh + (size_t)a * 128;
    const _Float16* vp = Hh + (size_t)b * 128;

    f32x4 acc[8];
    #pragma unroll
    for (int t = 0; t < 8; ++t) acc[t] = (f32x4){0.f, 0.f, 0.f, 0.f};

    #pragma unroll
    for (int c8 = 0; c8 < 4; ++c8) {
        const half8 u8 = *(const half8*)(up + (c8 << 5) + (q << 3));
        const half8 v8 = *(const half8*)(vp + (c8 << 5) + (q << 3));
        half8 d8 = u8 - v8;
        ushort8 du = *(ushort8*)&d8;
        du = du & (unsigned short)0x7FFF;          // |diff|
        const half8 ae = *(half8*)&du;             // even-chunk edge frag
        const half8 ao = u8 * v8;                  // odd-chunk  edge frag

        const int kb0 = ((c8 << 3) + q) ^ swz;        // even chunk 2*c8
        const int kb1 = ((c8 << 3) + 4 + q) ^ swz;    // odd  chunk 2*c8+1
        #pragma unroll
        for (int t = 0; t < 8; ++t) {
            const half8 b0 = *(const half8*)&w1t[((t << 4) + cb) * W1T_STRIDE + (kb0 << 3)];
            acc[t] = __builtin_amdgcn_mfma_f32_16x16x32_f16(b0, ae, acc[t], 0, 0, 0);
        }
        #pragma unroll
        for (int t = 0; t < 8; ++t) {
            const half8 b1f = *(const half8*)&w1t[((t << 4) + cb) * W1T_STRIDE + (kb1 << 3)];
            acc[t] = __builtin_amdgcn_mfma_f32_16x16x32_f16(b1f, ao, acc[t], 0, 0, 0);
        }
    }

    // K-chunk 8: edge side = [S, F, 1, 0...], w side = [w256; w257; b1; 0...]
    half8 aE;
    #pragma unroll
    for (int j = 0; j < 8; ++j) aE[j] = (_Float16)0.f;
    if (q == 0) {
        aE[0] = *(const _Float16*)&sl;
        aE[1] = *(const _Float16*)&fl;
        aE[2] = (_Float16)1.0f;
    }
    #pragma unroll
    for (int t = 0; t < 8; ++t) {
        const half8 bE = *(const half8*)&w1t[((t << 4) + cb) * W1T_STRIDE + ((32 + q) << 3)];
        acc[t] = __builtin_amdgcn_mfma_f32_16x16x32_f16(bE, aE, acc[t], 0, 0, 0);
    }

    // epilogue: rs = sum over this lane's 32 hidden rows, then q-reduce
    float rs = 0.f;
    #pragma unroll
    for (int t = 0; t < 8; ++t) {
        const f32x4 av = acc[t];
        const f32x4 wv = w2r[t];
        #pragma unroll
        for (int rr = 0; rr < 4; ++rr)
            rs += silu_f(av[rr]) * wv[rr];
    }
    rs += __shfl_xor(rs, 16);
    rs += __shfl_xor(rs, 32);

    if (q == 0 && ebase + cb < elim) out[r.z] = rs + b2v;
}

// ---------------- main kernel: 1024 threads, 256-edge tickets ----------------

__global__ __launch_bounds__(1024, 8)
void edgegate_seg(const _Float16* __restrict__ Hh,
                  const int4*  __restrict__ recs,
                  const int*   __restrict__ vbs,   // [9] segment edge bounds
                  int*         __restrict__ ctr,   // [8] per-segment ticket ctrs
                  const float* __restrict__ W1,
                  const float* __restrict__ b1,
                  const float* __restrict__ W2,
                  const float* __restrict__ b2,
                  float*       __restrict__ out)
{
    __shared__ _Float16 w1t[128 * W1T_STRIDE];   // 73,728 B; 2 blocks/CU
    __shared__ int tkt[2];                        // parity ticket slots
    const int tid = threadIdx.x;
    stage_w1(W1, b1, w1t, tid);

    int xcd;
    asm volatile("s_getreg_b32 %0, hwreg(HW_REG_XCC_ID)" : "=s"(xcd));
    xcd &= (NSEG - 1);

    const int lane = tid & 63;
    const int wave = tid >> 6;                    // 0..15
    const int q    = lane >> 4;
    const int cb   = lane & 15;
    const int swz  = cb & 7;
    const float b2v = b2[0];
    // per-lane w2 for hidden rows t*16 + q*4 + rr (swapped-C layout)
    f32x4 w2r[8];
    #pragma unroll
    for (int t = 0; t < 8; ++t)
        w2r[t] = *(const f32x4*)&W2[(t << 4) + (q << 2)];

    int p = 0;
    // own segment first, then steal (correct under any dispatch mapping)
    for (int sidx = 0; sidx < NSEG; ++sidx) {
        const int seg = (xcd + sidx) & (NSEG - 1);
        const int vs  = vbs[seg];
        const int ve  = vbs[seg + 1];
        const int ner = ve - vs;
        if (ner <= 0) continue;
        const int Tt = (ner + 255) >> 8;    // 256-edge tickets (16 waves x 16)

        __syncthreads();                    // tkt[p] free; covers w1t on sidx==0
        if (tid == 0) tkt[p] = atomicAdd(&ctr[seg], 1);
        __syncthreads();
        int t0 = tkt[p];
        while (t0 < Tt) {
            const int pn = p ^ 1;
            if (tid == 0) tkt[pn] = atomicAdd(&ctr[seg], 1);   // prefetch next
            const int ebase = vs + (t0 << 8) + (wave << 4);
            edge_tile16(Hh, recs, w1t, w2r, b2v, out, ebase, ve, q, cb, swz);
            __syncthreads();     // publishes tkt[pn]; paces the segment's blocks
            p = pn;
            t0 = tkt[p];
        }
    }
}

// ---------------- fallback (unsorted), 1024 threads ----------------

__global__ __launch_bounds__(1024, 8)
void edgegate_fb(const float* __restrict__ H,
                 const _Float16* __restrict__ Hh,
                 const int*   __restrict__ eidx,
                 const float* __restrict__ Se,
                 const float* __restrict__ Fe,
                 const float* __restrict__ W1,
                 const float* __restrict__ b1,
                 const float* __restrict__ W2,
                 const float* __restrict__ b2,
                 float*       __restrict__ out,
                 int E, int ntiles, int useF16)
{
    __shared__ _Float16 w1t[128 * W1T_STRIDE];
    const int tid = threadIdx.x;
    stage_w1(W1, b1, w1t, tid);

    const int lane = tid & 63;
    const int wave = tid >> 6;
    const int q    = lane >> 4;
    const int cb   = lane & 15;
    const int swz  = cb & 7;
    const float b2v = b2[0];
    f32x4 w2r[8];
    #pragma unroll
    for (int t = 0; t < 8; ++t)
        w2r[t] = *(const f32x4*)&W2[(t << 4) + (q << 2)];

    __syncthreads();

    for (int tile = blockIdx.x; tile < ntiles; tile += gridDim.x) {
        const int ebase = tile * 256 + wave * 16;
        int e = ebase + cb;
        if (e >= E) e = E - 1;
        const int u = eidx[e];
        const int v = eidx[E + e];
        const float sfe = Se[e];
        const float ffe = Fe[e];

        f32x4 acc[8];
        #pragma unroll
        for (int t = 0; t < 8; ++t) acc[t] = (f32x4){0.f, 0.f, 0.f, 0.f};

        #pragma unroll
        for (int c8 = 0; c8 < 4; ++c8) {
            half8 ae, ao;
            if (useF16) {
                const _Float16* up = Hh + (size_t)u * 128;
                const _Float16* vp = Hh + (size_t)v * 128;
                const half8 u8 = *(const half8*)(up + (c8 << 5) + (q << 3));
                const half8 v8 = *(const half8*)(vp + (c8 << 5) + (q << 3));
                half8 d8 = u8 - v8;
                ushort8 du = *(ushort8*)&d8;
                du = du & (unsigned short)0x7FFF;
                ae = *(half8*)&du;
                ao = u8 * v8;
            } else {
                const float* up = H + (size_t)u * 128;
                const float* vp = H + (size_t)v * 128;
                #pragma unroll
                for (int j = 0; j < 8; ++j) {
                    const float uu = up[(c8 << 5) + (q << 3) + j];
                    const float vv = vp[(c8 << 5) + (q << 3) + j];
                    ae[j] = (_Float16)fabsf(uu - vv);
                    ao[j] = (_Float16)(uu * vv);
                }
            }
            const int kb0 = ((c8 << 3) + q) ^ swz;
            const int kb1 = ((c8 << 3) + 4 + q) ^ swz;
            #pragma unroll
            for (int t = 0; t < 8; ++t) {
                const half8 b0 = *(const half8*)&w1t[((t << 4) + cb) * W1T_STRIDE + (kb0 << 3)];
                acc[t] = __builtin_amdgcn_mfma_f32_16x16x32_f16(b0, ae, acc[t], 0, 0, 0);
            }
            #pragma unroll
            for (int t = 0; t < 8; ++t) {
                const half8 b1f = *(const half8*)&w1t[((t << 4) + cb) * W1T_STRIDE + (kb1 << 3)];
                acc[t] = __builtin_amdgcn_mfma_f32_16x16x32_f16(b1f, ao, acc[t], 0, 0, 0);
            }
        }

        // K-chunk 8
        half8 aE;
        #pragma unroll
        for (int j = 0; j < 8; ++j) aE[j] = (_Float16)0.f;
        if (q == 0) {
            aE[0] = (_Float16)sfe;
            aE[1] = (_Float16)ffe;
            aE[2] = (_Float16)1.0f;
        }
        #pragma unroll
        for (int t = 0; t < 8; ++t) {
            const half8 bE = *(const half8*)&w1t[((t << 4) + cb) * W1T_STRIDE + ((32 + q) << 3)];
            acc[t] = __builtin_amdgcn_mfma_f32_16x16x32_f16(bE, aE, acc[t], 0, 0, 0);
        }

        float rs = 0.f;
        #pragma unroll
        for (int t = 0; t < 8; ++t) {
            const f32x4 av = acc[t];
            const f32x4 wv = w2r[t];
            #pragma unroll
            for (int rr = 0; rr < 4; ++rr)
                rs += silu_f(av[rr]) * wv[rr];
        }
        rs += __shfl_xor(rs, 16);
        rs += __shfl_xor(rs, 32);

        if (q == 0 && ebase + cb < E) out[ebase + cb] = rs + b2v;
    }
}

// ---------------- launch ----------------

static inline size_t align256(size_t x) { return (x + 255) & ~(size_t)255; }

extern "C" void kernel_launch(void* const* d_in, const int* in_sizes, int n_in,
                              void* d_out, int out_size, void* d_ws, size_t ws_size,
                              hipStream_t stream)
{
    const float* H    = (const float*)d_in[0];
    const int*   eidx = (const int*)  d_in[1];
    const float* Se   = (const float*)d_in[2];
    const float* Fe   = (const float*)d_in[3];
    const float* W1   = (const float*)d_in[4];
    const float* b1   = (const float*)d_in[5];
    const float* W2   = (const float*)d_in[6];
    const float* b2   = (const float*)d_in[7];
    float* out = (float*)d_out;

    const int nH     = in_sizes[0];            // 6.4M floats
    const int nNodes = nH / 128;               // 50000
    const int E      = in_sizes[2];            // 600000
    const int n4     = nH / 4;
    const int ntiles = (E + 255) / 256;        // 256-edge fb tiles

    const int ASZ   = (nNodes + NSEG - 1) / NSEG;   // 6250
    const int BBINS = (nNodes + 7) >> 3;            // 6250
    const int NB    = NSEG * BBINS;                 // 50000
    const int nb1   = (NB + 255) / 256;             // 196

    const size_t hhB    = (size_t)nH * sizeof(_Float16);
    const size_t off_g  = align256(hhB);                           // hist+ctr+flag
    const size_t off_bs = align256(off_g + (size_t)(NB + 16) * 4); // bsum
    const size_t off_vb = align256(off_bs + 256 * 4);              // vbs[9]
    const size_t off_r  = align256(off_vb + 16 * 4);               // recs
    const size_t need   = off_r + (size_t)E * sizeof(int4);

    if (ws_size >= need && nb1 <= 256) {
        _Float16* Hh   = (_Float16*)((char*)d_ws);
        int*      hist = (int*)     ((char*)d_ws + off_g);
        int*      ctr  = hist + NB;                       // 8 counters
        int*      flag = hist + NB + 8;                   // scan done-flag
        int*      bsum = (int*)     ((char*)d_ws + off_bs);
        int*      vbs  = (int*)     ((char*)d_ws + off_vb);
        int4*     recs = (int4*)    ((char*)d_ws + off_r);

        const int ncvh = (n4 > E) ? n4 : E;
        hipMemsetAsync(hist, 0, (size_t)(NB + 16) * sizeof(int), stream);
        hipLaunchKernelGGL(cvt_hist_kernel, dim3((ncvh + 255) / 256), dim3(256),
                           0, stream, H, Hh, n4, eidx, hist, E, ASZ, BBINS);
        hipLaunchKernelGGL(scan_kernel, dim3(nb1), dim3(256), 0, stream,
                           hist, bsum, NB, nb1, flag, vbs, BBINS, E);
        hipLaunchKernelGGL(scatter_kernel, dim3((E + 255) / 256), dim3(256),
                           0, stream, eidx, Se, Fe, hist, bsum, recs,
                           E, ASZ, BBINS);
        hipLaunchKernelGGL(edgegate_seg, dim3(256), dim3(1024), 0, stream,
                           Hh, recs, vbs, ctr, W1, b1, W2, b2, out);
    } else if (ws_size >= hhB) {
        _Float16* Hh = (_Float16*)d_ws;
        const int grid = (256 < ntiles) ? 256 : ntiles;
        hipLaunchKernelGGL(cvt_hist_kernel, dim3((n4 + 255) / 256), dim3(256),
                           0, stream, H, Hh, n4, eidx, (int*)nullptr, 0, 1, 1);
        hipLaunchKernelGGL(edgegate_fb, dim3(grid), dim3(1024), 0, stream,
                           H, Hh, eidx, Se, Fe, W1, b1, W2, b2, out, E, ntiles, 1);
    } else {
        const int grid = (256 < ntiles) ? 256 : ntiles;
        hipLaunchKernelGGL(edgegate_fb, dim3(grid), dim3(1024), 0, stream,
                           H, (const _Float16*)nullptr, eidx, Se, Fe, W1, b1, W2, b2,
                           out, E, ntiles, 0);
    }
}

// Round 9
// 278.105 us; speedup vs baseline: 1.1898x; 1.1898x over previous
//
#include <hip/hip_runtime.h>

// EdgeGate: out[e] = silu(f(e) @ W1 + b1) @ W2 + b2,
//   f(e) = [|H_u - H_v| (128), H_u*H_v (128), S_e, F_e]   (258)
//
// R21 (post-mortem of R20): occupancy-doubling theory untested -- R20's
// regression was a LAUNCH_BOUNDS SEMANTICS bug. Evidence: (1024,8) produced
// VGPR_Count=32 + scratch spill (FETCH 322MB, WRITE 151MB). Cap arithmetic
// across R16-R20 shows hipcc treats the 2nd arg as MIN WORKGROUPS/CU (CUDA
// semantics): (512,4) -> 2048/(4*8 waves)=64 cap (observed 52-64);
// (1024,8) -> 2048/(8*16)=16->32 cap (observed 32, spilled).
// Fix: __launch_bounds__(1024, 2) = 2 blocks x 16 waves = 32 waves/CU ->
// cap 64 >= the ~60 this kernel needs (R19). Under either semantics no
// spill. LDS 74KB x 2 = 148 <= 160KB. Everything else = R20:
//  - 1024-thread blocks, grid 256, 256-edge tickets (16 waves x 16 edges)
//  - R19 operand swap (epilogue = 32 silu-fma + 2 shfl_xor)
//  - ordered ticket queue + block-level prefetch (pacing, R12/R16)
//  - S/F/b1 in MFMA K-chunk 8; W2 in per-lane regs
//  - pre-pass: memset + cvt_hist + fused scan + scatter (R16 shape)

typedef _Float16       half8   __attribute__((ext_vector_type(8)));
typedef _Float16       half4v  __attribute__((ext_vector_type(4)));
typedef unsigned short ushort8 __attribute__((ext_vector_type(8)));
typedef float          f32x4   __attribute__((ext_vector_type(4)));

#define NSEG       8
#define W1T_STRIDE 288   // halves per n-row: 9 K-chunks x 32

__device__ __forceinline__ float silu_f(float x) {
    return x / (1.0f + __expf(-x));
}

__device__ __forceinline__ void canon(int u, int v, int& a, int& b) {
    const int sw = (u ^ v) & 1;       // balanced, symmetric in (u,v)
    a = sw ? v : u;
    b = sw ? u : v;
}

// ---------------- pre-passes ----------------
// hist[0..NB) + ctr(8) + flag(1) zeroed by one hipMemsetAsync.

// cvt fused with hist (R16 form: cvt overlaps the sort pipeline's front)
__global__ __launch_bounds__(256)
void cvt_hist_kernel(const float* __restrict__ H, _Float16* __restrict__ Hh,
                     int n4, const int* __restrict__ eidx,
                     int* __restrict__ hist, int E, int ASZ, int BBINS) {
    int i = blockIdx.x * blockDim.x + threadIdx.x;
    if (i < n4) {
        const float4 f = ((const float4*)H)[i];
        half4v h;
        h[0] = (_Float16)f.x; h[1] = (_Float16)f.y;
        h[2] = (_Float16)f.z; h[3] = (_Float16)f.w;
        ((half4v*)Hh)[i] = h;
    }
    if (i < E) {
        int a, b;
        canon(eidx[i], eidx[E + i], a, b);
        atomicAdd(&hist[(a / ASZ) * BBINS + (b >> 3)], 1);
    }
}

// fused scan1+scan2 (R18, validated): per-block exclusive scan, last block
// scans bsum and emits vbs. Cross-block reads via atomic RMW after
// threadfence/flag handshake.
__global__ __launch_bounds__(256)
void scan_kernel(int* __restrict__ hist, int* __restrict__ bsum,
                 int NB, int nb1, int* __restrict__ flag,
                 int* __restrict__ vbs, int BBINS, int E) {
    __shared__ int s[256];
    __shared__ int lastBlk;
    const int t = threadIdx.x;
    const int i = blockIdx.x * 256 + t;
    const int v = (i < NB) ? hist[i] : 0;
    s[t] = v;
    __syncthreads();
    for (int off = 1; off < 256; off <<= 1) {
        const int x = (t >= off) ? s[t - off] : 0;
        __syncthreads();
        s[t] += x;
        __syncthreads();
    }
    if (i < NB) hist[i] = s[t] - v;       // intra-block exclusive
    if (t == 255) bsum[blockIdx.x] = s[255];
    __threadfence();                       // publish before flag
    if (t == 0) lastBlk = (atomicAdd(flag, 1) == (int)gridDim.x - 1);
    __syncthreads();
    if (!lastBlk) return;
    const int bv = (t < nb1) ? atomicAdd(&bsum[t], 0) : 0;   // coherent read
    s[t] = bv;
    __syncthreads();
    for (int off = 1; off < 256; off <<= 1) {
        const int x = (t >= off) ? s[t - off] : 0;
        __syncthreads();
        s[t] += x;
        __syncthreads();
    }
    if (t < nb1) bsum[t] = s[t] - bv;     // exclusive
    __syncthreads();
    if (t < NSEG) {
        const int idx = t * BBINS;
        vbs[t] = atomicAdd(&hist[idx], 0) + bsum[idx >> 8];
    } else if (t == NSEG) {
        vbs[NSEG] = E;
    }
}

__global__ __launch_bounds__(256)
void scatter_kernel(const int* __restrict__ eidx, const float* __restrict__ Se,
                    const float* __restrict__ Fe, int* __restrict__ ofs,
                    const int* __restrict__ bsum,
                    int4* __restrict__ recs, int E, int ASZ, int BBINS) {
    int e = blockIdx.x * blockDim.x + threadIdx.x;
    if (e < E) {
        int a, b;
        canon(eidx[e], eidx[E + e], a, b);
        const int key = (a / ASZ) * BBINS + (b >> 3);
        const int pos = atomicAdd(&ofs[key], 1) + bsum[key >> 8];
        _Float16 sh = (_Float16)Se[e];
        _Float16 fh = (_Float16)Fe[e];
        unsigned pk = (unsigned)*(unsigned short*)&sh
                    | ((unsigned)*(unsigned short*)&fh << 16);
        recs[pos] = make_int4(a, b, e, (int)pk);
    }
}

// ---------------- W1 LDS staging (1024-thread version) ----------------
// w1t[n][kp] f16, kp = c*32 + k32, c = 0..8.
// c<8: src row = (c&1)*128 + (c>>1)*32 + k32. 16B blocks kb at kb^(n&7).
// c==8 (kb 32..35, UNswizzled): k32==0 -> W1 row 256, k32==1 -> row 257,
//      k32==2 -> b1, else 0.

__device__ __forceinline__ void stage_w1(const float* __restrict__ W1,
                                         const float* __restrict__ b1,
                                         _Float16* __restrict__ w1t, int tid) {
    const int n = tid & 127;
    const int g = tid >> 7;                // 0..7 (1024 threads)
    #pragma unroll
    for (int i = 0; i < 5; ++i) {
        const int kb = g + (i << 3);       // 0..39
        if (kb < 32) {
            half8 tmp;
            #pragma unroll
            for (int j = 0; j < 8; ++j) {
                const int kp  = (kb << 3) + j;
                const int c   = kp >> 5;
                const int k32 = kp & 31;
                const int src = ((c & 1) << 7) + ((c >> 1) << 5) + k32;
                tmp[j] = (_Float16)W1[src * 128 + n];
            }
            *(half8*)&w1t[n * W1T_STRIDE + ((kb ^ (n & 7)) << 3)] = tmp;
        } else if (kb < 36) {
            const int k32b = (kb - 32) << 3;   // 0,8,16,24
            half8 tmp;
            #pragma unroll
            for (int j = 0; j < 8; ++j) {
                const int k32 = k32b + j;
                float v = 0.f;
                if (k32 == 0)      v = W1[32768 + n];   // row 256
                else if (k32 == 1) v = W1[32896 + n];   // row 257
                else if (k32 == 2) v = b1[n];
                tmp[j] = (_Float16)v;
            }
            *(half8*)&w1t[n * W1T_STRIDE + (kb << 3)] = tmp;
        }
    }
}

// ---------------- main tile compute (one 16-edge group per wave) ----------------
// SWAPPED operands (R19): mfma(w_frag, edge_frag, acc) -> C[hidden][edge].
// Lane (q,cb): acc[t][rr] = h[hidden = t*16 + q*4 + rr][edge = cb].

__device__ __forceinline__ void edge_tile16(
    const _Float16* __restrict__ Hh, const int4* __restrict__ recs,
    const _Float16* __restrict__ w1t,
    const f32x4* __restrict__ w2r, float b2v, float* __restrict__ out,
    int ebase, int elim, int q, int cb, int swz)
{
    const int e = min(ebase + cb, elim - 1);     // clamp; store guarded
    const int4 r = recs[e];
    const int a = r.x, b = r.y;
    const unsigned pk = (unsigned)r.w;
    const unsigned short sl = (unsigned short)(pk & 0xFFFF);
    const unsigned short fl = (unsigned short)(pk >> 16);

    const _Float16* up = Hh + (size_t)a * 128;
    const _Float16* vp = Hh + (size_t)b * 128;

    f32x4 acc[8];
    #pragma unroll
    for (int t = 0; t < 8; ++t) acc[t] = (f32x4){0.f, 0.f, 0.f, 0.f};

    #pragma unroll
    for (int c8 = 0; c8 < 4; ++c8) {
        const half8 u8 = *(const half8*)(up + (c8 << 5) + (q << 3));
        const half8 v8 = *(const half8*)(vp + (c8 << 5) + (q << 3));
        half8 d8 = u8 - v8;
        ushort8 du = *(ushort8*)&d8;
        du = du & (unsigned short)0x7FFF;          // |diff|
        const half8 ae = *(half8*)&du;             // even-chunk edge frag
        const half8 ao = u8 * v8;                  // odd-chunk  edge frag

        const int kb0 = ((c8 << 3) + q) ^ swz;        // even chunk 2*c8
        const int kb1 = ((c8 << 3) + 4 + q) ^ swz;    // odd  chunk 2*c8+1
        #pragma unroll
        for (int t = 0; t < 8; ++t) {
            const half8 b0 = *(const half8*)&w1t[((t << 4) + cb) * W1T_STRIDE + (kb0 << 3)];
            acc[t] = __builtin_amdgcn_mfma_f32_16x16x32_f16(b0, ae, acc[t], 0, 0, 0);
        }
        #pragma unroll
        for (int t = 0; t < 8; ++t) {
            const half8 b1f = *(const half8*)&w1t[((t << 4) + cb) * W1T_STRIDE + (kb1 << 3)];
            acc[t] = __builtin_amdgcn_mfma_f32_16x16x32_f16(b1f, ao, acc[t], 0, 0, 0);
        }
    }

    // K-chunk 8: edge side = [S, F, 1, 0...], w side = [w256; w257; b1; 0...]
    half8 aE;
    #pragma unroll
    for (int j = 0; j < 8; ++j) aE[j] = (_Float16)0.f;
    if (q == 0) {
        aE[0] = *(const _Float16*)&sl;
        aE[1] = *(const _Float16*)&fl;
        aE[2] = (_Float16)1.0f;
    }
    #pragma unroll
    for (int t = 0; t < 8; ++t) {
        const half8 bE = *(const half8*)&w1t[((t << 4) + cb) * W1T_STRIDE + ((32 + q) << 3)];
        acc[t] = __builtin_amdgcn_mfma_f32_16x16x32_f16(bE, aE, acc[t], 0, 0, 0);
    }

    // epilogue: rs = sum over this lane's 32 hidden rows, then q-reduce
    float rs = 0.f;
    #pragma unroll
    for (int t = 0; t < 8; ++t) {
        const f32x4 av = acc[t];
        const f32x4 wv = w2r[t];
        #pragma unroll
        for (int rr = 0; rr < 4; ++rr)
            rs += silu_f(av[rr]) * wv[rr];
    }
    rs += __shfl_xor(rs, 16);
    rs += __shfl_xor(rs, 32);

    if (q == 0 && ebase + cb < elim) out[r.z] = rs + b2v;
}

// ---------------- main kernel: 1024 threads, 256-edge tickets ----------------

__global__ __launch_bounds__(1024, 2)
void edgegate_seg(const _Float16* __restrict__ Hh,
                  const int4*  __restrict__ recs,
                  const int*   __restrict__ vbs,   // [9] segment edge bounds
                  int*         __restrict__ ctr,   // [8] per-segment ticket ctrs
                  const float* __restrict__ W1,
                  const float* __restrict__ b1,
                  const float* __restrict__ W2,
                  const float* __restrict__ b2,
                  float*       __restrict__ out)
{
    __shared__ _Float16 w1t[128 * W1T_STRIDE];   // 73,728 B; 2 blocks/CU
    __shared__ int tkt[2];                        // parity ticket slots
    const int tid = threadIdx.x;
    stage_w1(W1, b1, w1t, tid);

    int xcd;
    asm volatile("s_getreg_b32 %0, hwreg(HW_REG_XCC_ID)" : "=s"(xcd));
    xcd &= (NSEG - 1);

    const int lane = tid & 63;
    const int wave = tid >> 6;                    // 0..15
    const int q    = lane >> 4;
    const int cb   = lane & 15;
    const int swz  = cb & 7;
    const float b2v = b2[0];
    // per-lane w2 for hidden rows t*16 + q*4 + rr (swapped-C layout)
    f32x4 w2r[8];
    #pragma unroll
    for (int t = 0; t < 8; ++t)
        w2r[t] = *(const f32x4*)&W2[(t << 4) + (q << 2)];

    int p = 0;
    // own segment first, then steal (correct under any dispatch mapping)
    for (int sidx = 0; sidx < NSEG; ++sidx) {
        const int seg = (xcd + sidx) & (NSEG - 1);
        const int vs  = vbs[seg];
        const int ve  = vbs[seg + 1];
        const int ner = ve - vs;
        if (ner <= 0) continue;
        const int Tt = (ner + 255) >> 8;    // 256-edge tickets (16 waves x 16)

        __syncthreads();                    // tkt[p] free; covers w1t on sidx==0
        if (tid == 0) tkt[p] = atomicAdd(&ctr[seg], 1);
        __syncthreads();
        int t0 = tkt[p];
        while (t0 < Tt) {
            const int pn = p ^ 1;
            if (tid == 0) tkt[pn] = atomicAdd(&ctr[seg], 1);   // prefetch next
            const int ebase = vs + (t0 << 8) + (wave << 4);
            edge_tile16(Hh, recs, w1t, w2r, b2v, out, ebase, ve, q, cb, swz);
            __syncthreads();     // publishes tkt[pn]; paces the segment's blocks
            p = pn;
            t0 = tkt[p];
        }
    }
}

// ---------------- fallback (unsorted), 1024 threads ----------------

__global__ __launch_bounds__(1024, 2)
void edgegate_fb(const float* __restrict__ H,
                 const _Float16* __restrict__ Hh,
                 const int*   __restrict__ eidx,
                 const float* __restrict__ Se,
                 const float* __restrict__ Fe,
                 const float* __restrict__ W1,
                 const float* __restrict__ b1,
                 const float* __restrict__ W2,
                 const float* __restrict__ b2,
                 float*       __restrict__ out,
                 int E, int ntiles, int useF16)
{
    __shared__ _Float16 w1t[128 * W1T_STRIDE];
    const int tid = threadIdx.x;
    stage_w1(W1, b1, w1t, tid);

    const int lane = tid & 63;
    const int wave = tid >> 6;
    const int q    = lane >> 4;
    const int cb   = lane & 15;
    const int swz  = cb & 7;
    const float b2v = b2[0];
    f32x4 w2r[8];
    #pragma unroll
    for (int t = 0; t < 8; ++t)
        w2r[t] = *(const f32x4*)&W2[(t << 4) + (q << 2)];

    __syncthreads();

    for (int tile = blockIdx.x; tile < ntiles; tile += gridDim.x) {
        const int ebase = tile * 256 + wave * 16;
        int e = ebase + cb;
        if (e >= E) e = E - 1;
        const int u = eidx[e];
        const int v = eidx[E + e];
        const float sfe = Se[e];
        const float ffe = Fe[e];

        f32x4 acc[8];
        #pragma unroll
        for (int t = 0; t < 8; ++t) acc[t] = (f32x4){0.f, 0.f, 0.f, 0.f};

        #pragma unroll
        for (int c8 = 0; c8 < 4; ++c8) {
            half8 ae, ao;
            if (useF16) {
                const _Float16* up = Hh + (size_t)u * 128;
                const _Float16* vp = Hh + (size_t)v * 128;
                const half8 u8 = *(const half8*)(up + (c8 << 5) + (q << 3));
                const half8 v8 = *(const half8*)(vp + (c8 << 5) + (q << 3));
                half8 d8 = u8 - v8;
                ushort8 du = *(ushort8*)&d8;
                du = du & (unsigned short)0x7FFF;
                ae = *(half8*)&du;
                ao = u8 * v8;
            } else {
                const float* up = H + (size_t)u * 128;
                const float* vp = H + (size_t)v * 128;
                #pragma unroll
                for (int j = 0; j < 8; ++j) {
                    const float uu = up[(c8 << 5) + (q << 3) + j];
                    const float vv = vp[(c8 << 5) + (q << 3) + j];
                    ae[j] = (_Float16)fabsf(uu - vv);
                    ao[j] = (_Float16)(uu * vv);
                }
            }
            const int kb0 = ((c8 << 3) + q) ^ swz;
            const int kb1 = ((c8 << 3) + 4 + q) ^ swz;
            #pragma unroll
            for (int t = 0; t < 8; ++t) {
                const half8 b0 = *(const half8*)&w1t[((t << 4) + cb) * W1T_STRIDE + (kb0 << 3)];
                acc[t] = __builtin_amdgcn_mfma_f32_16x16x32_f16(b0, ae, acc[t], 0, 0, 0);
            }
            #pragma unroll
            for (int t = 0; t < 8; ++t) {
                const half8 b1f = *(const half8*)&w1t[((t << 4) + cb) * W1T_STRIDE + (kb1 << 3)];
                acc[t] = __builtin_amdgcn_mfma_f32_16x16x32_f16(b1f, ao, acc[t], 0, 0, 0);
            }
        }

        // K-chunk 8
        half8 aE;
        #pragma unroll
        for (int j = 0; j < 8; ++j) aE[j] = (_Float16)0.f;
        if (q == 0) {
            aE[0] = (_Float16)sfe;
            aE[1] = (_Float16)ffe;
            aE[2] = (_Float16)1.0f;
        }
        #pragma unroll
        for (int t = 0; t < 8; ++t) {
            const half8 bE = *(const half8*)&w1t[((t << 4) + cb) * W1T_STRIDE + ((32 + q) << 3)];
            acc[t] = __builtin_amdgcn_mfma_f32_16x16x32_f16(bE, aE, acc[t], 0, 0, 0);
        }

        float rs = 0.f;
        #pragma unroll
        for (int t = 0; t < 8; ++t) {
            const f32x4 av = acc[t];
            const f32x4 wv = w2r[t];
            #pragma unroll
            for (int rr = 0; rr < 4; ++rr)
                rs += silu_f(av[rr]) * wv[rr];
        }
        rs += __shfl_xor(rs, 16);
        rs += __shfl_xor(rs, 32);

        if (q == 0 && ebase + cb < E) out[ebase + cb] = rs + b2v;
    }
}

// ---------------- launch ----------------

static inline size_t align256(size_t x) { return (x + 255) & ~(size_t)255; }

extern "C" void kernel_launch(void* const* d_in, const int* in_sizes, int n_in,
                              void* d_out, int out_size, void* d_ws, size_t ws_size,
                              hipStream_t stream)
{
    const float* H    = (const float*)d_in[0];
    const int*   eidx = (const int*)  d_in[1];
    const float* Se   = (const float*)d_in[2];
    const float* Fe   = (const float*)d_in[3];
    const float* W1   = (const float*)d_in[4];
    const float* b1   = (const float*)d_in[5];
    const float* W2   = (const float*)d_in[6];
    const float* b2   = (const float*)d_in[7];
    float* out = (float*)d_out;

    const int nH     = in_sizes[0];            // 6.4M floats
    const int nNodes = nH / 128;               // 50000
    const int E      = in_sizes[2];            // 600000
    const int n4     = nH / 4;
    const int ntiles = (E + 255) / 256;        // 256-edge fb tiles

    const int ASZ   = (nNodes + NSEG - 1) / NSEG;   // 6250
    const int BBINS = (nNodes + 7) >> 3;            // 6250
    const int NB    = NSEG * BBINS;                 // 50000
    const int nb1   = (NB + 255) / 256;             // 196

    const size_t hhB    = (size_t)nH * sizeof(_Float16);
    const size_t off_g  = align256(hhB);                           // hist+ctr+flag
    const size_t off_bs = align256(off_g + (size_t)(NB + 16) * 4); // bsum
    const size_t off_vb = align256(off_bs + 256 * 4);              // vbs[9]
    const size_t off_r  = align256(off_vb + 16 * 4);               // recs
    const size_t need   = off_r + (size_t)E * sizeof(int4);

    if (ws_size >= need && nb1 <= 256) {
        _Float16* Hh   = (_Float16*)((char*)d_ws);
        int*      hist = (int*)     ((char*)d_ws + off_g);
        int*      ctr  = hist + NB;                       // 8 counters
        int*      flag = hist + NB + 8;                   // scan done-flag
        int*      bsum = (int*)     ((char*)d_ws + off_bs);
        int*      vbs  = (int*)     ((char*)d_ws + off_vb);
        int4*     recs = (int4*)    ((char*)d_ws + off_r);

        const int ncvh = (n4 > E) ? n4 : E;
        hipMemsetAsync(hist, 0, (size_t)(NB + 16) * sizeof(int), stream);
        hipLaunchKernelGGL(cvt_hist_kernel, dim3((ncvh + 255) / 256), dim3(256),
                           0, stream, H, Hh, n4, eidx, hist, E, ASZ, BBINS);
        hipLaunchKernelGGL(scan_kernel, dim3(nb1), dim3(256), 0, stream,
                           hist, bsum, NB, nb1, flag, vbs, BBINS, E);
        hipLaunchKernelGGL(scatter_kernel, dim3((E + 255) / 256), dim3(256),
                           0, stream, eidx, Se, Fe, hist, bsum, recs,
                           E, ASZ, BBINS);
        hipLaunchKernelGGL(edgegate_seg, dim3(256), dim3(1024), 0, stream,
                           Hh, recs, vbs, ctr, W1, b1, W2, b2, out);
    } else if (ws_size >= hhB) {
        _Float16* Hh = (_Float16*)d_ws;
        const int grid = (256 < ntiles) ? 256 : ntiles;
        hipLaunchKernelGGL(cvt_hist_kernel, dim3((n4 + 255) / 256), dim3(256),
                           0, stream, H, Hh, n4, eidx, (int*)nullptr, 0, 1, 1);
        hipLaunchKernelGGL(edgegate_fb, dim3(grid), dim3(1024), 0, stream,
                           H, Hh, eidx, Se, Fe, W1, b1, W2, b2, out, E, ntiles, 1);
    } else {
        const int grid = (256 < ntiles) ? 256 : ntiles;
        hipLaunchKernelGGL(edgegate_fb, dim3(grid), dim3(1024), 0, stream,
                           H, (const _Float16*)nullptr, eidx, Se, Fe, W1, b1, W2, b2,
                           out, E, ntiles, 0);
    }
}